// Round 1
// 10607.388 us; speedup vs baseline: 1.4228x; 1.4228x over previous
//
#include <hip/hip_runtime.h>
#include <cstddef>
#include <cstdint>

// ---------------------------------------------------------------------------
// LSTM  B=64 T=512 I=H=1024
// Phase A: pack weights -> bf16 N-major transposes + bias concat
// Phase B: xproj[t][b][4H] = bf16( x @ [wii|wif|wig|wio] + b )   (MFMA GEMM)
// Phase C: persistent recurrent kernel, 256 co-resident blocks, Wh in LDS,
//          per-block progress publish + poll-all pseudo-barrier per timestep
//          (no serialized RMW, no per-poll-iteration buffer_inv).
// ---------------------------------------------------------------------------

typedef __bf16 bf16_t;
typedef __bf16 bf16x8 __attribute__((ext_vector_type(8)));
typedef __bf16 bf16x4 __attribute__((ext_vector_type(4)));
typedef float  f32x4  __attribute__((ext_vector_type(4)));

#define MFMA16(a, b, c) __builtin_amdgcn_mfma_f32_16x16x32_bf16((a), (b), (c), 0, 0, 0)

// ---- problem constants ----
#define BB   64          // batch
#define TT   512         // time steps
#define HH   1024        // hidden = input
#define G4H  4096        // 4*H
#define MM   (BB * TT)   // 32768 GEMM rows

// ---- workspace layout (bytes) ----
#define XPROJ_OFF  0ull                               // [T][B][4H] bf16 = 256 MB
#define WX_OFF     268435456ull                       // Wx^T [4096][1024] bf16 = 8 MB
#define WH_OFF     (WX_OFF + 8388608ull)              // Wh^T [4096][1024] bf16 = 8 MB
#define BC_OFF     (WH_OFF + 8388608ull)              // bias concat f32[4096]
#define HB_OFF     (BC_OFF + 16384ull)                // h double buffer 2*64*1024 bf16
#define BAR_OFF    (HB_OFF + 262144ull)               // per-block progress array [256] u32

__device__ __forceinline__ float fsig(float x) {
    return 1.0f / (1.0f + __expf(-x));
}
__device__ __forceinline__ float ftanh(float x) {
    return 1.0f - 2.0f / (__expf(2.0f * x) + 1.0f);
}

// ---------------------------------------------------------------------------
// Transpose-pack: src fp32 [1024 k][1024 h]  ->  dst bf16 [h][k] (N-major).
// blockIdx.z selects which of the 8 weight matrices; 64x64 tiles.
// ---------------------------------------------------------------------------
__global__ void transpose_pack(const float* __restrict__ s0, const float* __restrict__ s1,
                               const float* __restrict__ s2, const float* __restrict__ s3,
                               const float* __restrict__ s4, const float* __restrict__ s5,
                               const float* __restrict__ s6, const float* __restrict__ s7,
                               bf16_t* __restrict__ wxt, bf16_t* __restrict__ wht) {
    __shared__ float tile[64][65];
    const int z = blockIdx.z;
    const float* src = (z == 0) ? s0 : (z == 1) ? s1 : (z == 2) ? s2 : (z == 3) ? s3
                      : (z == 4) ? s4 : (z == 5) ? s5 : (z == 6) ? s6 : s7;
    bf16_t* dst = ((z < 4) ? wxt : wht) + (size_t)(z & 3) * 1024 * 1024;
    const int k0 = blockIdx.x * 64, h0 = blockIdx.y * 64;
    const int t = threadIdx.x;
#pragma unroll
    for (int i = 0; i < 16; ++i) {
        int kk = (t >> 6) * 16 + i, hh = t & 63;
        tile[kk][hh] = src[(size_t)(k0 + kk) * 1024 + h0 + hh];
    }
    __syncthreads();
#pragma unroll
    for (int i = 0; i < 16; ++i) {
        int hh = (t >> 6) * 16 + i, kk = t & 63;
        dst[(size_t)(h0 + hh) * 1024 + k0 + kk] = (bf16_t)tile[kk][hh];
    }
}

__global__ void pack_bias(const float* __restrict__ bi, const float* __restrict__ bf_,
                          const float* __restrict__ bg, const float* __restrict__ bo,
                          float* __restrict__ bc) {
    int n = blockIdx.x * 256 + threadIdx.x;   // 0..4095
    int g = n >> 10, h = n & 1023;
    const float* s = (g == 0) ? bi : (g == 1) ? bf_ : (g == 2) ? bg : bo;
    bc[n] = s[h];
}

// ---------------------------------------------------------------------------
// Phase B GEMM: xproj[(t*64+b)][n] = sum_k x[b*512+t][k] * WxT[n][k] + bc[n]
// 128x128 tile, BK=64, 256 threads (4 waves, each 64x64), bf16 MFMA 16x16x32.
// ---------------------------------------------------------------------------
__global__ __launch_bounds__(256, 2) void gemm_xproj(
    const float* __restrict__ x, const bf16_t* __restrict__ wx,
    const float* __restrict__ bc, bf16_t* __restrict__ xp) {
    __shared__ bf16_t Als[128][72];   // row stride 144B (16B aligned, conflict-light)
    __shared__ bf16_t Bls[128][72];
    const int tid = threadIdx.x;
    const int n0 = blockIdx.x * 128, m0 = blockIdx.y * 128;
    const int lane = tid & 63, w = tid >> 6;
    const int wm = w >> 1, wn = w & 1;
    const int col = lane & 15, quad = lane >> 4;
    const int rowA = tid >> 4, ksegA = (tid & 15) * 4;   // A staging map
    const int rowB = tid >> 3, chunkB = tid & 7;         // B staging map
    f32x4 acc[4][4] = {};

    for (int kt = 0; kt < 16; ++kt) {
        const int k0 = kt * 64;
        __syncthreads();
        // stage A (fp32 -> bf16 on the fly): 128 rows x 64 k
#pragma unroll
        for (int i = 0; i < 8; ++i) {
            int r = rowA + i * 16;
            float4 v = *(const float4*)&x[(size_t)(m0 + r) * 1024 + k0 + ksegA];
            bf16x4 pv = { (bf16_t)v.x, (bf16_t)v.y, (bf16_t)v.z, (bf16_t)v.w };
            *(bf16x4*)&Als[r][ksegA] = pv;
        }
        // stage B (already bf16, N-major): 128 rows x 64 k
#pragma unroll
        for (int i = 0; i < 4; ++i) {
            int r = rowB + i * 32;
            *(bf16x8*)&Bls[r][chunkB * 8] =
                *(const bf16x8*)&wx[(size_t)(n0 + r) * 1024 + k0 + chunkB * 8];
        }
        __syncthreads();
#pragma unroll
        for (int kq = 0; kq < 64; kq += 32) {
            bf16x8 a[4], b[4];
#pragma unroll
            for (int s = 0; s < 4; ++s) {
                a[s] = *(const bf16x8*)&Als[wm * 64 + s * 16 + col][kq + quad * 8];
                b[s] = *(const bf16x8*)&Bls[wn * 64 + s * 16 + col][kq + quad * 8];
            }
#pragma unroll
            for (int sm = 0; sm < 4; ++sm)
#pragma unroll
                for (int sn = 0; sn < 4; ++sn)
                    acc[sm][sn] = MFMA16(a[sm], b[sn], acc[sm][sn]);
        }
    }
    // epilogue: +bias, permute rows m=b*512+t -> t*64+b, store bf16
#pragma unroll
    for (int sm = 0; sm < 4; ++sm) {
        int mbase = m0 + wm * 64 + sm * 16 + quad * 4;
#pragma unroll
        for (int sn = 0; sn < 4; ++sn) {
            int n = n0 + wn * 64 + sn * 16 + col;
            float bias = bc[n];
#pragma unroll
            for (int reg = 0; reg < 4; ++reg) {
                int mm = mbase + reg;
                int b = mm >> 9, t = mm & 511;
                xp[(size_t)((t << 6) + b) * 4096 + n] = (bf16_t)(acc[sm][sn][reg] + bias);
            }
        }
    }
}

// ---------------------------------------------------------------------------
// Phase C: persistent recurrence. 256 blocks x 256 threads, all co-resident.
// Block bid owns H-columns [bid*4, bid*4+4): 16 gate columns (i,f,g,o x 4).
// Wh slice (16 x 1024 bf16) resident in LDS for all 512 steps.
//
// Per-step sync = publish/poll pseudo-barrier:
//   publisher: release-fence(agent) -> relaxed store bar[bid]=t+1  (no RMW)
//   poller:    wave 0, relaxed loads of all 256 slots (4/lane), __all reduce,
//              s_sleep backoff; ONE acquire-fence(agent) after success.
// This removes (a) 256 serialized same-line atomic RMWs per step and
// (b) the buffer_inv emitted by every acquire-load poll iteration.
// ---------------------------------------------------------------------------
__global__ __launch_bounds__(256, 1) void lstm_rec(
    const bf16_t* __restrict__ xproj, const bf16_t* __restrict__ whc,
    bf16_t* __restrict__ hbuf, float* __restrict__ out,
    unsigned int* __restrict__ bar) {
    __shared__ bf16_t wh[16][1032];   // row stride 2064B -> 2-way (free) on b128 reads
    __shared__ float  gl[64][17];     // gates scratch for the i/f/g/o re-shuffle
    const int tid = threadIdx.x;
    const int bid = blockIdx.x;

    // stage Wh slice: rows r=(g*4+c) <- WhT[g*1024 + bid*4 + c][:]
    {
        int r = tid >> 4, sub = tid & 15;
        int n = (r >> 2) * 1024 + bid * 4 + (r & 3);
        const bf16_t* src = whc + (size_t)n * 1024;
#pragma unroll
        for (int j = 0; j < 8; ++j) {
            int e = (j * 16 + sub) * 8;
            *(bf16x8*)&wh[r][e] = *(const bf16x8*)&src[e];
        }
    }
    __syncthreads();

    const int w = tid >> 6, lane = tid & 63;
    const int col = lane & 15, quad = lane >> 4;
    const int rowA = w * 16 + col;        // A-operand batch row
    const int bb0  = w * 16 + quad * 4;   // C-layout batch row base
    const int b2 = tid >> 2, cc = tid & 3;
    const int hcol = bid * 4 + cc;
    const int ng = (col >> 2) * 1024 + bid * 4 + (col & 3);  // packed gate col

    float cstate = 0.0f;
    float* hseq = out;                          // [64][512][1024]
    float* hT = out + (size_t)BB * TT * HH;     // [64][1024]
    float* cT = hT + BB * HH;                   // [64][1024]

    // xproj prefetch registers (loaded for t=0 here; for t+1 during the poll)
    float xpre[4];
#pragma unroll
    for (int reg = 0; reg < 4; ++reg)
        xpre[reg] = (float)xproj[(size_t)(bb0 + reg) * 4096 + ng];

    for (int t = 0; t < TT; ++t) {
        const bf16_t* hprev = hbuf + (size_t)(t & 1) * (BB * HH);
        bf16_t* hnext = hbuf + (size_t)((t + 1) & 1) * (BB * HH);

        // prefetch whole h row-slice for this wave (16 rows x 1024 k)
        bf16x8 af[32];
#pragma unroll
        for (int kq = 0; kq < 32; ++kq)
            af[kq] = *(const bf16x8*)&hprev[rowA * 1024 + kq * 32 + quad * 8];

        f32x4 acc = {0.f, 0.f, 0.f, 0.f};
#pragma unroll
        for (int kq = 0; kq < 32; ++kq) {
            bf16x8 bfr = *(const bf16x8*)&wh[col][kq * 32 + quad * 8];
            acc = MFMA16(af[kq], bfr, acc);
        }

        // gates = h@Wh + xproj  -> LDS in (b, gatecol) layout
#pragma unroll
        for (int reg = 0; reg < 4; ++reg) {
            int bb = bb0 + reg;
            gl[bb][col] = acc[reg] + xpre[reg];
        }
        __syncthreads();

        // per-(batch, hcol) activations; c stays in a register
        float iv = fsig(gl[b2][cc]);
        float fv = fsig(gl[b2][4 + cc]);
        float gv = ftanh(gl[b2][8 + cc]);
        float ov = fsig(gl[b2][12 + cc]);
        cstate = fv * cstate + iv * gv;
        float hv = ov * ftanh(cstate);

        // hseq/hT/cT are write-once outputs: nontemporal keeps them out of the
        // per-step release-fence L2 writeback set.
        __builtin_nontemporal_store(hv, &hseq[(size_t)b2 * (TT * HH) + t * HH + hcol]);
        hnext[b2 * HH + hcol] = (bf16_t)hv;   // cross-block data: normal store
        if (t == TT - 1) {
            __builtin_nontemporal_store(hv, &hT[b2 * HH + hcol]);
            __builtin_nontemporal_store(cstate, &cT[b2 * HH + hcol]);
        }

        if (t < TT - 1) {
            __syncthreads();   // all waves' h-stores ack'd in L2 (vmcnt drained)
            const unsigned tgt = (unsigned)(t + 1);
            const size_t xoff = (size_t)((t + 1) * 64 + bb0) * 4096 + ng;
            if (w == 0) {
                if (lane == 0) {
                    // release: flush this XCD's dirty L2 (h) to the coherent point
                    __builtin_amdgcn_fence(__ATOMIC_RELEASE, "agent");
                    __hip_atomic_store(&bar[bid], tgt, __ATOMIC_RELAXED,
                                       __HIP_MEMORY_SCOPE_AGENT);
                }
                // keep the xproj prefetch below the fence/publish
                asm volatile("" ::: "memory");
#pragma unroll
                for (int reg = 0; reg < 4; ++reg)
                    xpre[reg] = (float)xproj[xoff + (size_t)reg * 4096];
                unsigned int* sl = bar + lane * 4;   // 64 lanes x 4 slots = 256
                for (;;) {
                    unsigned v0 = __hip_atomic_load(sl + 0, __ATOMIC_RELAXED,
                                                    __HIP_MEMORY_SCOPE_AGENT);
                    unsigned v1 = __hip_atomic_load(sl + 1, __ATOMIC_RELAXED,
                                                    __HIP_MEMORY_SCOPE_AGENT);
                    unsigned v2 = __hip_atomic_load(sl + 2, __ATOMIC_RELAXED,
                                                    __HIP_MEMORY_SCOPE_AGENT);
                    unsigned v3 = __hip_atomic_load(sl + 3, __ATOMIC_RELAXED,
                                                    __HIP_MEMORY_SCOPE_AGENT);
                    int ok = (v0 >= tgt) & (v1 >= tgt) & (v2 >= tgt) & (v3 >= tgt);
                    if (__all(ok)) break;
                    __builtin_amdgcn_s_sleep(2);
                }
                // acquire: single cache-inv so the fresh h is read from LLC
                __builtin_amdgcn_fence(__ATOMIC_ACQUIRE, "agent");
            } else {
                // waves 1..3: prefetch next xproj while wave 0 polls
#pragma unroll
                for (int reg = 0; reg < 4; ++reg)
                    xpre[reg] = (float)xproj[xoff + (size_t)reg * 4096];
            }
            __syncthreads();
        }
    }
}

// ---------------------------------------------------------------------------
extern "C" void kernel_launch(void* const* d_in, const int* in_sizes, int n_in,
                              void* d_out, int out_size, void* d_ws, size_t ws_size,
                              hipStream_t stream) {
    (void)in_sizes; (void)n_in; (void)out_size; (void)ws_size;
    const float* x   = (const float*)d_in[0];
    const float* wii = (const float*)d_in[1];
    const float* whi = (const float*)d_in[2];
    const float* bi  = (const float*)d_in[3];
    const float* wif = (const float*)d_in[4];
    const float* whf = (const float*)d_in[5];
    const float* bfb = (const float*)d_in[6];
    const float* wig = (const float*)d_in[7];
    const float* whg = (const float*)d_in[8];
    const float* bg  = (const float*)d_in[9];
    const float* wio = (const float*)d_in[10];
    const float* who = (const float*)d_in[11];
    const float* bo  = (const float*)d_in[12];

    char* ws = (char*)d_ws;
    bf16_t*   xp   = (bf16_t*)(ws + XPROJ_OFF);
    bf16_t*   wxt  = (bf16_t*)(ws + WX_OFF);
    bf16_t*   wht  = (bf16_t*)(ws + WH_OFF);
    float*    bc   = (float*)(ws + BC_OFF);
    bf16_t*   hbuf = (bf16_t*)(ws + HB_OFF);
    unsigned* bar  = (unsigned*)(ws + BAR_OFF);

    // zero h double-buffer + progress array (contiguous region)
    hipMemsetAsync(hbuf, 0, 262144 + 4096, stream);

    transpose_pack<<<dim3(16, 16, 8), 256, 0, stream>>>(wii, wif, wig, wio,
                                                        whi, whf, whg, who, wxt, wht);
    pack_bias<<<16, 256, 0, stream>>>(bi, bfb, bg, bo, bc);
    gemm_xproj<<<dim3(32, 256), 256, 0, stream>>>(x, wxt, bc, xp);
    lstm_rec<<<256, 256, 0, stream>>>(xp, wht, hbuf, (float*)d_out, bar);
}

// Round 2
// 4722.879 us; speedup vs baseline: 3.1955x; 2.2460x over previous
//
#include <hip/hip_runtime.h>
#include <cstddef>
#include <cstdint>

// ---------------------------------------------------------------------------
// LSTM  B=64 T=512 I=H=1024
// Phase A: pack weights -> bf16 N-major transposes + bias concat
// Phase B: xproj[t][b][4H] = bf16( x @ [wii|wif|wig|wio] + b )   (MFMA GEMM)
// Phase C: persistent recurrence, 256 co-resident blocks, FENCE-FREE sync:
//   - h exchanged via write-through (sc1) stores + cache-bypass (sc0 sc1) loads
//     -> no buffer_wbl2 / buffer_inv per step at all
//   - hierarchical barrier: arrivals -> bar[bid]; block 0 reduces and
//     publishes one 'go' word; 255 blocks poll a single hot LLC line.
// ---------------------------------------------------------------------------

typedef __bf16 bf16_t;
typedef __bf16 bf16x8 __attribute__((ext_vector_type(8)));
typedef __bf16 bf16x4 __attribute__((ext_vector_type(4)));
typedef float  f32x4  __attribute__((ext_vector_type(4)));

#define MFMA16(a, b, c) __builtin_amdgcn_mfma_f32_16x16x32_bf16((a), (b), (c), 0, 0, 0)

// ---- problem constants ----
#define BB   64          // batch
#define TT   512         // time steps
#define HH   1024        // hidden = input
#define G4H  4096        // 4*H

// ---- workspace layout (bytes) ----
#define XPROJ_OFF  0ull                               // [T][B][4H] bf16 = 256 MB
#define WX_OFF     268435456ull                       // Wx^T [4096][1024] bf16 = 8 MB
#define WH_OFF     (WX_OFF + 8388608ull)              // Wh^T [4096][1024] bf16 = 8 MB
#define BC_OFF     (WH_OFF + 8388608ull)              // bias concat f32[4096]
#define HB_OFF     (BC_OFF + 16384ull)                // h double buffer 2*64*1024 bf16
#define BAR_OFF    (HB_OFF + 262144ull)               // bar[256] + go word

__device__ __forceinline__ float fsig(float x) {
    return 1.0f / (1.0f + __expf(-x));
}
__device__ __forceinline__ float ftanh(float x) {
    return 1.0f - 2.0f / (__expf(2.0f * x) + 1.0f);
}

// ---------------------------------------------------------------------------
// Transpose-pack: src fp32 [1024 k][1024 h]  ->  dst bf16 [h][k] (N-major).
// ---------------------------------------------------------------------------
__global__ void transpose_pack(const float* __restrict__ s0, const float* __restrict__ s1,
                               const float* __restrict__ s2, const float* __restrict__ s3,
                               const float* __restrict__ s4, const float* __restrict__ s5,
                               const float* __restrict__ s6, const float* __restrict__ s7,
                               bf16_t* __restrict__ wxt, bf16_t* __restrict__ wht) {
    __shared__ float tile[64][65];
    const int z = blockIdx.z;
    const float* src = (z == 0) ? s0 : (z == 1) ? s1 : (z == 2) ? s2 : (z == 3) ? s3
                      : (z == 4) ? s4 : (z == 5) ? s5 : (z == 6) ? s6 : s7;
    bf16_t* dst = ((z < 4) ? wxt : wht) + (size_t)(z & 3) * 1024 * 1024;
    const int k0 = blockIdx.x * 64, h0 = blockIdx.y * 64;
    const int t = threadIdx.x;
#pragma unroll
    for (int i = 0; i < 16; ++i) {
        int kk = (t >> 6) * 16 + i, hh = t & 63;
        tile[kk][hh] = src[(size_t)(k0 + kk) * 1024 + h0 + hh];
    }
    __syncthreads();
#pragma unroll
    for (int i = 0; i < 16; ++i) {
        int hh = (t >> 6) * 16 + i, kk = t & 63;
        dst[(size_t)(h0 + hh) * 1024 + k0 + kk] = (bf16_t)tile[kk][hh];
    }
}

__global__ void pack_bias(const float* __restrict__ bi, const float* __restrict__ bf_,
                          const float* __restrict__ bg, const float* __restrict__ bo,
                          float* __restrict__ bc) {
    int n = blockIdx.x * 256 + threadIdx.x;   // 0..4095
    int g = n >> 10, h = n & 1023;
    const float* s = (g == 0) ? bi : (g == 1) ? bf_ : (g == 2) ? bg : bo;
    bc[n] = s[h];
}

// ---------------------------------------------------------------------------
// Phase B GEMM: xproj[(t*64+b)][n] = sum_k x[b*512+t][k] * WxT[n][k] + bc[n]
// ---------------------------------------------------------------------------
__global__ __launch_bounds__(256, 2) void gemm_xproj(
    const float* __restrict__ x, const bf16_t* __restrict__ wx,
    const float* __restrict__ bc, bf16_t* __restrict__ xp) {
    __shared__ bf16_t Als[128][72];
    __shared__ bf16_t Bls[128][72];
    const int tid = threadIdx.x;
    const int n0 = blockIdx.x * 128, m0 = blockIdx.y * 128;
    const int lane = tid & 63, w = tid >> 6;
    const int wm = w >> 1, wn = w & 1;
    const int col = lane & 15, quad = lane >> 4;
    const int rowA = tid >> 4, ksegA = (tid & 15) * 4;
    const int rowB = tid >> 3, chunkB = tid & 7;
    f32x4 acc[4][4] = {};

    for (int kt = 0; kt < 16; ++kt) {
        const int k0 = kt * 64;
        __syncthreads();
#pragma unroll
        for (int i = 0; i < 8; ++i) {
            int r = rowA + i * 16;
            float4 v = *(const float4*)&x[(size_t)(m0 + r) * 1024 + k0 + ksegA];
            bf16x4 pv = { (bf16_t)v.x, (bf16_t)v.y, (bf16_t)v.z, (bf16_t)v.w };
            *(bf16x4*)&Als[r][ksegA] = pv;
        }
#pragma unroll
        for (int i = 0; i < 4; ++i) {
            int r = rowB + i * 32;
            *(bf16x8*)&Bls[r][chunkB * 8] =
                *(const bf16x8*)&wx[(size_t)(n0 + r) * 1024 + k0 + chunkB * 8];
        }
        __syncthreads();
#pragma unroll
        for (int kq = 0; kq < 64; kq += 32) {
            bf16x8 a[4], b[4];
#pragma unroll
            for (int s = 0; s < 4; ++s) {
                a[s] = *(const bf16x8*)&Als[wm * 64 + s * 16 + col][kq + quad * 8];
                b[s] = *(const bf16x8*)&Bls[wn * 64 + s * 16 + col][kq + quad * 8];
            }
#pragma unroll
            for (int sm = 0; sm < 4; ++sm)
#pragma unroll
                for (int sn = 0; sn < 4; ++sn)
                    acc[sm][sn] = MFMA16(a[sm], b[sn], acc[sm][sn]);
        }
    }
#pragma unroll
    for (int sm = 0; sm < 4; ++sm) {
        int mbase = m0 + wm * 64 + sm * 16 + quad * 4;
#pragma unroll
        for (int sn = 0; sn < 4; ++sn) {
            int n = n0 + wn * 64 + sn * 16 + col;
            float bias = bc[n];
#pragma unroll
            for (int reg = 0; reg < 4; ++reg) {
                int mm = mbase + reg;
                int b = mm >> 9, t = mm & 511;
                xp[(size_t)((t << 6) + b) * 4096 + n] = (bf16_t)(acc[sm][sn][reg] + bias);
            }
        }
    }
}

// ---------------------------------------------------------------------------
// Phase C: persistent recurrence, fence-free.
// Block bid owns H-columns [bid*4, bid*4+4): 16 gate columns.
// ---------------------------------------------------------------------------
__global__ __launch_bounds__(256, 1) void lstm_rec(
    const bf16_t* __restrict__ xproj, const bf16_t* __restrict__ whc,
    bf16_t* __restrict__ hbuf, float* __restrict__ out,
    unsigned int* __restrict__ bar) {
    __shared__ bf16_t wh[16][1032];                 // Wh slice, LDS-resident
    __shared__ float  gl[64][17];                   // gate scratch (intra-wave only)
    __shared__ __align__(8) unsigned short gl2[64][4];  // packed h for write-through
    const int tid = threadIdx.x;
    const int bid = blockIdx.x;
    unsigned int* goflag = bar + 384;               // separate line from bar[0..255]

    // stage Wh slice: rows r=(g*4+c) <- WhT[g*1024 + bid*4 + c][:]
    {
        int r = tid >> 4, sub = tid & 15;
        int n = (r >> 2) * 1024 + bid * 4 + (r & 3);
        const bf16_t* src = whc + (size_t)n * 1024;
#pragma unroll
        for (int j = 0; j < 8; ++j) {
            int e = (j * 16 + sub) * 8;
            *(bf16x8*)&wh[r][e] = *(const bf16x8*)&src[e];
        }
    }
    __syncthreads();

    const int w = tid >> 6, lane = tid & 63;
    const int col = lane & 15, quad = lane >> 4;
    const int rowA = w * 16 + col;        // A-operand batch row
    const int bb0  = w * 16 + quad * 4;   // C-layout batch row base
    const int b2 = tid >> 2, cc = tid & 3;
    const int hcol = bid * 4 + cc;
    const int ng = (col >> 2) * 1024 + bid * 4 + (col & 3);  // packed gate col

    float cstate = 0.0f;
    float* hseq = out;                          // [64][512][1024]
    float* hT = out + (size_t)BB * TT * HH;     // [64][1024]
    float* cT = hT + BB * HH;                   // [64][1024]

    // xproj prefetch registers (t=0 here; t+1 during the barrier window)
    float xpre[4];
#pragma unroll
    for (int reg = 0; reg < 4; ++reg)
        xpre[reg] = (float)xproj[(size_t)(bb0 + reg) * 4096 + ng];

    for (int t = 0; t < TT; ++t) {
        const bf16_t* hprev = hbuf + (size_t)(t & 1) * (BB * HH);
        bf16_t* hnext = hbuf + (size_t)((t + 1) & 1) * (BB * HH);

        // --- h gather: cache-bypass loads (sc0 sc1) straight from LLC.
        // Write-through stores put h there; bypass makes stale L1/L2 impossible.
        const bf16_t* hbase = hprev + (size_t)rowA * 1024 + quad * 8;
        bf16x8 af[32];
#define LDH(i, o) asm volatile("global_load_dwordx4 %0, %1, off offset:" o " sc0 sc1" \
                               : "=v"(af[i]) : "v"(hbase))
        LDH(0, "0");     LDH(1, "64");    LDH(2, "128");   LDH(3, "192");
        LDH(4, "256");   LDH(5, "320");   LDH(6, "384");   LDH(7, "448");
        LDH(8, "512");   LDH(9, "576");   LDH(10, "640");  LDH(11, "704");
        LDH(12, "768");  LDH(13, "832");  LDH(14, "896");  LDH(15, "960");
        LDH(16, "1024"); LDH(17, "1088"); LDH(18, "1152"); LDH(19, "1216");
        LDH(20, "1280"); LDH(21, "1344"); LDH(22, "1408"); LDH(23, "1472");
        LDH(24, "1536"); LDH(25, "1600"); LDH(26, "1664"); LDH(27, "1728");
        LDH(28, "1792"); LDH(29, "1856"); LDH(30, "1920"); LDH(31, "1984");
#undef LDH
        asm volatile("s_waitcnt vmcnt(0)" ::: "memory");
        __builtin_amdgcn_sched_barrier(0);

        f32x4 acc = {0.f, 0.f, 0.f, 0.f};
#pragma unroll
        for (int kq = 0; kq < 32; ++kq) {
            bf16x8 bfr = *(const bf16x8*)&wh[col][kq * 32 + quad * 8];
            acc = MFMA16(af[kq], bfr, acc);
        }

        // gates -> LDS. gl rows [16w,16w+16) are written AND read by wave w only,
        // so no __syncthreads needed here (compiler inserts the lgkmcnt wait).
#pragma unroll
        for (int reg = 0; reg < 4; ++reg) {
            int bb = bb0 + reg;
            gl[bb][col] = acc[reg] + xpre[reg];
        }

        // per-(batch, hcol) activations; c stays in a register
        float iv = fsig(gl[b2][cc]);
        float fv = fsig(gl[b2][4 + cc]);
        float gv = ftanh(gl[b2][8 + cc]);
        float ov = fsig(gl[b2][12 + cc]);
        cstate = fv * cstate + iv * gv;
        float hv = ov * ftanh(cstate);

        __builtin_nontemporal_store(hv, &hseq[(size_t)b2 * (TT * HH) + t * HH + hcol]);
        bf16_t hvb = (bf16_t)hv;
        gl2[b2][cc] = *(const unsigned short*)&hvb;   // collect for packed store

        if (t == TT - 1) {
            __builtin_nontemporal_store(hv, &hT[b2 * HH + hcol]);
            __builtin_nontemporal_store(cstate, &cT[b2 * HH + hcol]);
            break;                                    // no barrier after last step
        }

        __syncthreads();   // gl2 complete (written by all 4 waves)

        const unsigned tgt = (unsigned)(t + 1);
        const size_t xoff = (size_t)((t + 1) * 64 + bb0) * 4096 + ng;
        if (w == 0) {
            // write-through h publish: lane j stores batch j's 4 columns as one
            // u64 agent-scope store (global_store_dwordx2 sc1 -> LLC, no wbl2).
            unsigned long long pk = *(const unsigned long long*)&gl2[lane][0];
            __hip_atomic_store((unsigned long long*)(hnext + (size_t)lane * HH + bid * 4),
                               pk, __ATOMIC_RELAXED, __HIP_MEMORY_SCOPE_AGENT);
            asm volatile("s_waitcnt vmcnt(0)" ::: "memory");   // h at LLC before arrival
            if (lane == 0)
                __hip_atomic_store(&bar[bid], tgt, __ATOMIC_RELAXED,
                                   __HIP_MEMORY_SCOPE_AGENT);
            // prefetch next xproj below the publish
            asm volatile("" ::: "memory");
#pragma unroll
            for (int reg = 0; reg < 4; ++reg)
                xpre[reg] = (float)xproj[xoff + (size_t)reg * 4096];

            if (bid == 0) {
                // master: reduce all 256 arrivals, then publish 'go'
                unsigned int* sl = bar + lane * 4;
                for (;;) {
                    unsigned v0 = __hip_atomic_load(sl + 0, __ATOMIC_RELAXED,
                                                    __HIP_MEMORY_SCOPE_AGENT);
                    unsigned v1 = __hip_atomic_load(sl + 1, __ATOMIC_RELAXED,
                                                    __HIP_MEMORY_SCOPE_AGENT);
                    unsigned v2 = __hip_atomic_load(sl + 2, __ATOMIC_RELAXED,
                                                    __HIP_MEMORY_SCOPE_AGENT);
                    unsigned v3 = __hip_atomic_load(sl + 3, __ATOMIC_RELAXED,
                                                    __HIP_MEMORY_SCOPE_AGENT);
                    int ok = (v0 >= tgt) & (v1 >= tgt) & (v2 >= tgt) & (v3 >= tgt);
                    if (__all(ok)) break;
                    __builtin_amdgcn_s_sleep(2);
                }
                if (lane == 0)
                    __hip_atomic_store(goflag, tgt, __ATOMIC_RELAXED,
                                       __HIP_MEMORY_SCOPE_AGENT);
            } else {
                // 255 blocks poll ONE line (coalesced: one request per wave per round)
                for (;;) {
                    unsigned g = __hip_atomic_load(goflag, __ATOMIC_RELAXED,
                                                   __HIP_MEMORY_SCOPE_AGENT);
                    if (g >= tgt) break;
                    __builtin_amdgcn_s_sleep(2);
                }
            }
        } else {
            // waves 1..3: prefetch next xproj while wave 0 runs the barrier
#pragma unroll
            for (int reg = 0; reg < 4; ++reg)
                xpre[reg] = (float)xproj[xoff + (size_t)reg * 4096];
        }
        __syncthreads();   // releases waves 1..3; orders next h loads after 'go'
    }
}

// ---------------------------------------------------------------------------
extern "C" void kernel_launch(void* const* d_in, const int* in_sizes, int n_in,
                              void* d_out, int out_size, void* d_ws, size_t ws_size,
                              hipStream_t stream) {
    (void)in_sizes; (void)n_in; (void)out_size; (void)ws_size;
    const float* x   = (const float*)d_in[0];
    const float* wii = (const float*)d_in[1];
    const float* whi = (const float*)d_in[2];
    const float* bi  = (const float*)d_in[3];
    const float* wif = (const float*)d_in[4];
    const float* whf = (const float*)d_in[5];
    const float* bfb = (const float*)d_in[6];
    const float* wig = (const float*)d_in[7];
    const float* whg = (const float*)d_in[8];
    const float* bg  = (const float*)d_in[9];
    const float* wio = (const float*)d_in[10];
    const float* who = (const float*)d_in[11];
    const float* bo  = (const float*)d_in[12];

    char* ws = (char*)d_ws;
    bf16_t*   xp   = (bf16_t*)(ws + XPROJ_OFF);
    bf16_t*   wxt  = (bf16_t*)(ws + WX_OFF);
    bf16_t*   wht  = (bf16_t*)(ws + WH_OFF);
    float*    bc   = (float*)(ws + BC_OFF);
    bf16_t*   hbuf = (bf16_t*)(ws + HB_OFF);
    unsigned* bar  = (unsigned*)(ws + BAR_OFF);

    // zero h double-buffer + arrival array + go flag (contiguous region)
    hipMemsetAsync(hbuf, 0, 262144 + 4096, stream);

    transpose_pack<<<dim3(16, 16, 8), 256, 0, stream>>>(wii, wif, wig, wio,
                                                        whi, whf, whg, who, wxt, wht);
    pack_bias<<<16, 256, 0, stream>>>(bi, bfb, bg, bo, bc);
    gemm_xproj<<<dim3(32, 256), 256, 0, stream>>>(x, wxt, bc, xp);
    lstm_rec<<<256, 256, 0, stream>>>(xp, wht, hbuf, (float*)d_out, bar);
}